// Round 9
// baseline (202.910 us; speedup 1.0000x reference)
//
#include <hip/hip_runtime.h>

// AdaptedGaussianConditional: v = inputs - means; nearest-codebook symbol via
// exact lower_bound semantics (tie -> lower index); dequant = codebook[sym] + means.
// Outputs concatenated: [dequant fp32 N | symbols-as-f32 N].
//
// R9: single-gather LUT. R0-R8 invariant at ~63us traced to per-element
// DIVERGENT GATHER serialization (2 gathers x ~50 unique lines/wave ~ 100 TA
// cy/step ~ 32us/CU), not LDS/occupancy/compute. New entry exploits sym(v)
// monotonicity: per bucket, evaluate the EXACT reference decision at guard
// points; if sym spans <=1 step, entry {uv[s1], uv[s2], s1} resolves the
// element with ONE 16-B gather + exact pairwise fabs compare (ties -> lower,
// identical to reference; global argmin is in {s1,s2} so pairwise == global).
// >=2-boundary buckets (~4% mass at NB=1024): masked exact scan from stored A.

#define LVL 256
#define NB  1024
#define QPT 4

typedef float f32x4 __attribute__((ext_vector_type(4)));

// Shared by build & main kernels — MUST be bit-identical in both.
__device__ __forceinline__ int bucket_of(float v, float lo, float scale) {
    int b = (int)floorf((v - lo) * scale);
    return min(max(b, 0), NB - 1);
}

// exact reference nearest-symbol on a 256-entry sorted table in LDS
__device__ __forceinline__ int sym_exact(float x, const float* s_uv) {
    int l = 0, h = LVL;
    #pragma unroll
    for (int s = 0; s < 8; ++s) {
        int m = (l + h) >> 1;
        bool r = (s_uv[m] < x);
        l = r ? (m + 1) : l;
        h = r ? h : m;
    }
    int idx = min(max(l, 1), LVL - 1);
    float left = s_uv[idx - 1], right = s_uv[idx];
    return (fabsf(x - left) <= fabsf(x - right)) ? idx - 1 : idx;
}

// #{uv < x}
__device__ __forceinline__ int lb_count(float x, const float* s_uv) {
    int l = 0, h = LVL;
    #pragma unroll
    for (int s = 0; s < 8; ++s) {
        int m = (l + h) >> 1;
        bool r = (s_uv[m] < x);
        l = r ? (m + 1) : l;
        h = r ? h : m;
    }
    return l;
}

// ---------------- build kernel ----------------
// lut[b] = {uv[s1], uv[s2], pack, 0}
//   pack >= 0 : direct bucket; s1 = pack, s2 differs by <=1; sym/value via
//               exact pairwise fabs compare between .x and .y
//   pack <  0 : fallback; exact scan start A = -pack - 1
__global__ __launch_bounds__(256) void agc_build_lut(
    const float* __restrict__ uv, float4* __restrict__ lut)
{
    __shared__ float s_uv[LVL];
    int t = threadIdx.x;
    s_uv[t] = uv[t];
    __syncthreads();

    const float lo    = s_uv[0];
    const float rng   = s_uv[LVL - 1] - lo;
    const float width = rng / (float)NB;

    #pragma unroll
    for (int q = 0; q < NB / 256; ++q) {
        int b = q * 256 + t;
        // guard window: one bucket of slop on each side covers fp rounding in
        // bucket_of (same construction as R1, which measured absmax == 0)
        float g_lo = lo + (float)(b - 1) * width;
        float g_hi = lo + (float)(b + 2) * width;

        // monotone bracket of sym over all v assigned to this bucket
        int s1 = (b == 0)      ? 0         : sym_exact(g_lo, s_uv);
        int s2 = (b == NB - 1) ? (LVL - 1) : sym_exact(g_hi, s_uv);

        float4 e;
        if (s2 - s1 <= 1) {
            e.x = s_uv[s1];
            e.y = s_uv[s2];                       // == e.x when s1 == s2
            e.z = __int_as_float(s1);
            e.w = 0.f;
        } else {
            int A = (b == 0) ? 0 : lb_count(g_lo, s_uv);  // valid lower_bound start
            e.x = 0.f; e.y = 0.f;
            e.z = __int_as_float(-(A + 1));
            e.w = 0.f;
        }
        lut[b] = e;
    }
}

// ---------------- main kernel: NO LDS, NO barrier, ONE gather/element ----------
__global__ __launch_bounds__(256) void agc_quant_lut(
    const float* __restrict__ inputs,
    const float* __restrict__ means,
    const float* __restrict__ uv,
    const f32x4* __restrict__ lut,
    float* __restrict__ out_deq,
    float* __restrict__ out_sym,
    int n4, int n, int nfull)
{
    // uniform scalar loads — bit-identical lo/scale expression vs build
    const float lo    = uv[0];
    const float scale = (float)NB / (uv[LVL - 1] - lo);

    int t = threadIdx.x;
    const int i0 = blockIdx.x * (256 * QPT) + t;
    const bool full = (blockIdx.x < nfull);

    // ---- load phase: all 2*QPT stream loads in flight ----
    float4 in[QPT], mn[QPT];
    if (full) {
        #pragma unroll
        for (int k = 0; k < QPT; ++k) {
            int i = i0 + k * 256;
            in[k] = reinterpret_cast<const float4*>(inputs)[i];
            mn[k] = reinterpret_cast<const float4*>(means)[i];
        }
    } else {
        #pragma unroll
        for (int k = 0; k < QPT; ++k) {
            int i = i0 + k * 256;
            if (i < n4) {
                in[k] = reinterpret_cast<const float4*>(inputs)[i];
                mn[k] = reinterpret_cast<const float4*>(means)[i];
            }
        }
    }

    // ---- compute + store per quad ----
    #pragma unroll
    for (int k = 0; k < QPT; ++k) {
        int i = i0 + k * 256;
        if (!full && i >= n4) continue;

        float vs[4] = {in[k].x - mn[k].x, in[k].y - mn[k].y,
                       in[k].z - mn[k].z, in[k].w - mn[k].w};
        float ms[4] = {mn[k].x, mn[k].y, mn[k].z, mn[k].w};
        float dq[4], sy[4];

        // 4 bucket indices, then 4 single-b128 gathers issued together (ILP)
        int bx[4];
        #pragma unroll
        for (int e = 0; e < 4; ++e) bx[e] = bucket_of(vs[e], lo, scale);

        f32x4 E[4];
        #pragma unroll
        for (int e = 0; e < 4; ++e) E[e] = lut[bx[e]];

        #pragma unroll
        for (int e = 0; e < 4; ++e) {
            float v = vs[e];
            int pk = __float_as_int(E[e].z);

            float val; int sym;
            if (pk >= 0) {
                // exact pairwise decision between the bracketing candidates;
                // identical tie rule (<=, tie -> lower) as the reference
                bool tl = (fabsf(v - E[e].x) <= fabsf(v - E[e].y));
                sym = pk + (tl ? 0 : 1);
                val = tl ? E[e].x : E[e].y;
            } else {
                // rare masked path: exact lower_bound scan from valid start
                int s = -pk - 1;
                while (s < LVL && uv[s] < v) ++s;
                int idx = min(max(s, 1), LVL - 1);
                float left  = uv[idx - 1];
                float right = uv[idx];
                bool tl = (fabsf(v - left) <= fabsf(v - right));
                sym = tl ? (idx - 1) : idx;
                val = tl ? left : right;
            }

            sy[e] = (float)sym;
            dq[e] = val + ms[e];
        }

        reinterpret_cast<float4*>(out_deq)[i] = make_float4(dq[0], dq[1], dq[2], dq[3]);
        reinterpret_cast<float4*>(out_sym)[i] = make_float4(sy[0], sy[1], sy[2], sy[3]);
    }

    // tail (n % 4 != 0) — n here is 12.58M, rem = 0
    if (blockIdx.x == 0 && t == 0) {
        for (int j = n4 * 4; j < n; ++j) {
            float m = means[j];
            float v = inputs[j] - m;
            int l = 0, h = LVL;
            for (int s = 0; s < 8; ++s) {
                int mm = (l + h) >> 1;
                bool r = (uv[mm] < v);
                l = r ? (mm + 1) : l;
                h = r ? h : mm;
            }
            int idx = min(max(l, 1), LVL - 1);
            float left = uv[idx - 1], right = uv[idx];
            bool tl = fabsf(v - left) <= fabsf(v - right);
            out_deq[j] = (tl ? left : right) + m;
            out_sym[j] = (float)(tl ? idx - 1 : idx);
        }
    }
}

// ---------------- safety fallback (no/short workspace): binary-search kernel ----
__global__ __launch_bounds__(256) void agc_quant_fallback(
    const float* __restrict__ inputs,
    const float* __restrict__ means,
    const float* __restrict__ uv,
    float* __restrict__ out_deq,
    float* __restrict__ out_sym,
    int n4, int n)
{
    __shared__ float s_uv[LVL];
    s_uv[threadIdx.x] = uv[threadIdx.x];
    __syncthreads();

    int i = blockIdx.x * blockDim.x + threadIdx.x;
    if (i < n4) {
        float4 in = reinterpret_cast<const float4*>(inputs)[i];
        float4 mn = reinterpret_cast<const float4*>(means)[i];
        float vs[4] = {in.x - mn.x, in.y - mn.y, in.z - mn.z, in.w - mn.w};
        float ms[4] = {mn.x, mn.y, mn.z, mn.w};
        float dq[4], sy[4];
        #pragma unroll
        for (int k = 0; k < 4; ++k) {
            float v = vs[k];
            int lo = 0, hi = LVL;
            #pragma unroll
            for (int s = 0; s < 8; ++s) {
                int mid = (lo + hi) >> 1;
                bool r = (s_uv[mid] < v);
                lo = r ? (mid + 1) : lo;
                hi = r ? hi : mid;
            }
            int idx = min(max(lo, 1), LVL - 1);
            float left = s_uv[idx - 1], right = s_uv[idx];
            bool tl = (fabsf(v - left) <= fabsf(v - right));
            sy[k] = (float)(tl ? idx - 1 : idx);
            dq[k] = (tl ? left : right) + ms[k];
        }
        reinterpret_cast<float4*>(out_deq)[i] = make_float4(dq[0], dq[1], dq[2], dq[3]);
        reinterpret_cast<float4*>(out_sym)[i] = make_float4(sy[0], sy[1], sy[2], sy[3]);
    }
    if (blockIdx.x == 0 && threadIdx.x == 0) {
        for (int j = n4 * 4; j < n; ++j) {
            float m = means[j];
            float v = inputs[j] - m;
            int lo = 0, hi = LVL;
            for (int s = 0; s < 8; ++s) {
                int mid = (lo + hi) >> 1;
                bool r = (s_uv[mid] < v);
                lo = r ? (mid + 1) : lo;
                hi = r ? hi : mid;
            }
            int idx = min(max(lo, 1), LVL - 1);
            float left = s_uv[idx - 1], right = s_uv[idx];
            bool tl = fabsf(v - left) <= fabsf(v - right);
            out_deq[j] = (tl ? left : right) + m;
            out_sym[j] = (float)(tl ? idx - 1 : idx);
        }
    }
}

extern "C" void kernel_launch(void* const* d_in, const int* in_sizes, int n_in,
                              void* d_out, int out_size, void* d_ws, size_t ws_size,
                              hipStream_t stream)
{
    const float* inputs = (const float*)d_in[0];
    const float* means  = (const float*)d_in[1];
    const float* uv     = (const float*)d_in[2];

    int n  = in_sizes[0];        // 12,582,912
    int n4 = n / 4;

    float* out     = (float*)d_out;
    float* out_deq = out;        // first N: dequant
    float* out_sym = out + n;    // second N: symbols (exact float values)

    size_t need = (size_t)NB * sizeof(float4);       // 16 KB
    if (d_ws != nullptr && ws_size >= need) {
        float4* lut = (float4*)d_ws;
        agc_build_lut<<<1, 256, 0, stream>>>(uv, lut);

        int per_blk = 256 * QPT;                       // quads per block
        int nfull   = n4 / per_blk;                    // fully-covered blocks
        int blocks  = (n4 + per_blk - 1) / per_blk;    // 3072 for this shape
        if (blocks < 1) blocks = 1;
        agc_quant_lut<<<blocks, 256, 0, stream>>>(
            inputs, means, uv, (const f32x4*)lut,
            out_deq, out_sym, n4, n, nfull);
    } else {
        int blocks = (n4 + 255) / 256;
        if (blocks < 1) blocks = 1;
        agc_quant_fallback<<<blocks, 256, 0, stream>>>(
            inputs, means, uv, out_deq, out_sym, n4, n);
    }
}

// Round 10
// 193.831 us; speedup vs baseline: 1.0468x; 1.0468x over previous
//
#include <hip/hip_runtime.h>

// AdaptedGaussianConditional: v = inputs - means; nearest-codebook symbol via
// exact lower_bound semantics (tie -> lower index); dequant = codebook[sym] + means.
// Outputs concatenated: [dequant fp32 N | symbols-as-f32 N].
//
// R10: single-gather LUT with EXACT decision thresholds (no guard band).
// sym(v) = #{j : NOT g_j(v)}, g_j(v) = |v-uv[j]| <= |v-uv[j+1]| (monotone).
// Build finds each g_j's exact float flip point t_j by bisection over
// monotone float-bit keys (evaluating g_j with identical float ops), buckets
// them with the bit-identical bucket map -> per-bucket {A, cnt} with zero
// slop. cnt<=1 (~97% mass at NB=1024): ONE 16B L1 gather + exact pairwise
// compare. cnt>=2: bounded parallel correction from a 1KB threshold table.
// Streams: nontemporal loads (keep LUT L1-resident; R9 dropped this and
// regressed). Stores: normal cached (nt stores regressed in R6).

#define LVL 256
#define NB  1024
#define QPT 4

typedef float f32x4 __attribute__((ext_vector_type(4)));

// Shared by build & main kernels — MUST be bit-identical in both.
__device__ __forceinline__ int bucket_of(float v, float lo, float scale) {
    int b = (int)floorf((v - lo) * scale);
    return min(max(b, 0), NB - 1);
}

// float <-> monotone uint key (IEEE total order)
__device__ __forceinline__ unsigned f2k(float f) {
    unsigned u = __float_as_uint(f);
    return (u & 0x80000000u) ? ~u : (u | 0x80000000u);
}
__device__ __forceinline__ float k2f(unsigned k) {
    unsigned u = (k & 0x80000000u) ? (k & 0x7fffffffu) : ~k;
    return __uint_as_float(u);
}

// ---------------- build kernel: NB/256 blocks ----------------
// lut[b] = {c1, c2, A, cnt}:
//   cnt<=1: candidates c1=uv[A], c2=uv[A+cnt]; exact pairwise fabs compare
//   cnt>=2: sym = A + sum_{jj<cnt} (v >= thr[A+jj]); val = uv[sym]
// thr[j] = exact float flip point of g_j (smallest float where g_j false)
__global__ __launch_bounds__(256) void agc_build_lut(
    const float* __restrict__ uv, float4* __restrict__ lut, float* __restrict__ thr)
{
    __shared__ float s_uv[LVL];
    __shared__ float s_t[LVL];      // t_j for j in [0, 255)
    __shared__ int   s_beta[LVL];   // bucket of t_j
    int t = threadIdx.x;
    s_uv[t] = uv[t];
    __syncthreads();
    const float lo    = s_uv[0];
    const float scale = (float)NB / (s_uv[LVL - 1] - lo);

    if (t < LVL - 1) {
        float a = s_uv[t], b = s_uv[t + 1];
        float tj;
        if (a == b) {
            tj = __builtin_inff();             // degenerate: g always true
        } else {
            // invariant: g(k2f(klo)) true, g(k2f(khi)) false
            unsigned klo = f2k(a), khi = f2k(b);
            while (khi - klo > 1u) {
                unsigned km = klo + (khi - klo) / 2u;
                float vm = k2f(km);
                if (fabsf(vm - a) <= fabsf(vm - b)) klo = km; else khi = km;
            }
            tj = k2f(khi);                     // smallest float where g false
        }
        s_t[t]    = tj;
        s_beta[t] = (tj == __builtin_inff()) ? (NB - 1) : bucket_of(tj, lo, scale);
        if (blockIdx.x == 0) thr[t] = tj;
    }
    __syncthreads();

    int b = blockIdx.x * 256 + t;              // b < NB (grid sized exactly)
    int A = 0, cnt = 0;
    for (int j = 0; j < LVL - 1; ++j) {        // broadcast LDS reads, cheap
        int bj = s_beta[j];
        A   += (bj <  b);
        cnt += (bj == b);
    }
    // A + cnt <= 255, so uv indices below are in range
    float4 e;
    if (cnt <= 1) {
        e.x = s_uv[A];
        e.y = s_uv[A + cnt];                   // == e.x when cnt == 0
    } else {
        e.x = 0.f;
        e.y = 0.f;
    }
    e.z = __int_as_float(A);
    e.w = __int_as_float(cnt);
    lut[b] = e;
}

// ---------------- main kernel: NO LDS, NO barrier, ONE gather/element --------
__global__ __launch_bounds__(256) void agc_quant_lut(
    const float* __restrict__ inputs,
    const float* __restrict__ means,
    const float* __restrict__ uv,
    const f32x4* __restrict__ lut,
    const float* __restrict__ thr,
    float* __restrict__ out_deq,
    float* __restrict__ out_sym,
    int n4, int n, int nfull)
{
    // uniform scalar loads — bit-identical lo/scale expression vs build
    const float lo    = uv[0];
    const float scale = (float)NB / (uv[LVL - 1] - lo);

    int t = threadIdx.x;
    const int i0 = blockIdx.x * (256 * QPT) + t;
    const bool full = (blockIdx.x < nfull);

    // ---- load phase: all 2*QPT nt stream loads in flight ----
    f32x4 in[QPT], mn[QPT];
    if (full) {
        #pragma unroll
        for (int k = 0; k < QPT; ++k) {
            int i = i0 + k * 256;
            in[k] = __builtin_nontemporal_load(reinterpret_cast<const f32x4*>(inputs) + i);
            mn[k] = __builtin_nontemporal_load(reinterpret_cast<const f32x4*>(means) + i);
        }
    } else {
        #pragma unroll
        for (int k = 0; k < QPT; ++k) {
            int i = i0 + k * 256;
            if (i < n4) {
                in[k] = __builtin_nontemporal_load(reinterpret_cast<const f32x4*>(inputs) + i);
                mn[k] = __builtin_nontemporal_load(reinterpret_cast<const f32x4*>(means) + i);
            }
        }
    }

    // ---- compute + store per quad ----
    #pragma unroll
    for (int k = 0; k < QPT; ++k) {
        int i = i0 + k * 256;
        if (!full && i >= n4) continue;

        float vs[4] = {in[k].x - mn[k].x, in[k].y - mn[k].y,
                       in[k].z - mn[k].z, in[k].w - mn[k].w};
        float ms[4] = {mn[k].x, mn[k].y, mn[k].z, mn[k].w};
        float dq[4], sy[4];

        // 4 bucket indices, then 4 single-b128 gathers issued together (ILP)
        int bx[4];
        #pragma unroll
        for (int e = 0; e < 4; ++e) bx[e] = bucket_of(vs[e], lo, scale);

        f32x4 E[4];
        #pragma unroll
        for (int e = 0; e < 4; ++e) E[e] = lut[bx[e]];

        #pragma unroll
        for (int e = 0; e < 4; ++e) {
            float v   = vs[e];
            int   A   = __float_as_int(E[e].z);
            int   cnt = __float_as_int(E[e].w);

            float val; int sym;
            if (cnt <= 1) {
                // exact pairwise decision (== reference comparator g_A when
                // cnt==1; trivially sym=A when cnt==0 since c1==c2)
                bool tl = (fabsf(v - E[e].x) <= fabsf(v - E[e].y));
                sym = tl ? A : A + 1;
                val = tl ? E[e].x : E[e].y;
            } else {
                // rare (~2.6% mass): bounded correction, independent L1-hot
                // loads from the 1KB exact-threshold table
                int s = A;
                for (int jj = 0; jj < cnt; ++jj)
                    s += (v >= thr[A + jj]) ? 1 : 0;
                sym = s;
                val = uv[s];
            }

            sy[e] = (float)sym;
            dq[e] = val + ms[e];
        }

        reinterpret_cast<float4*>(out_deq)[i] = make_float4(dq[0], dq[1], dq[2], dq[3]);
        reinterpret_cast<float4*>(out_sym)[i] = make_float4(sy[0], sy[1], sy[2], sy[3]);
    }

    // tail (n % 4 != 0) — n here is 12.58M, rem = 0
    if (blockIdx.x == 0 && t == 0) {
        for (int j = n4 * 4; j < n; ++j) {
            float m = means[j];
            float v = inputs[j] - m;
            int l = 0, h = LVL;
            for (int s = 0; s < 8; ++s) {
                int mm = (l + h) >> 1;
                bool r = (uv[mm] < v);
                l = r ? (mm + 1) : l;
                h = r ? h : mm;
            }
            int idx = min(max(l, 1), LVL - 1);
            float left = uv[idx - 1], right = uv[idx];
            bool tl = fabsf(v - left) <= fabsf(v - right);
            out_deq[j] = (tl ? left : right) + m;
            out_sym[j] = (float)(tl ? idx - 1 : idx);
        }
    }
}

// ---------------- safety fallback (no/short workspace): binary-search kernel ----
__global__ __launch_bounds__(256) void agc_quant_fallback(
    const float* __restrict__ inputs,
    const float* __restrict__ means,
    const float* __restrict__ uv,
    float* __restrict__ out_deq,
    float* __restrict__ out_sym,
    int n4, int n)
{
    __shared__ float s_uv[LVL];
    s_uv[threadIdx.x] = uv[threadIdx.x];
    __syncthreads();

    int i = blockIdx.x * blockDim.x + threadIdx.x;
    if (i < n4) {
        float4 in = reinterpret_cast<const float4*>(inputs)[i];
        float4 mn = reinterpret_cast<const float4*>(means)[i];
        float vs[4] = {in.x - mn.x, in.y - mn.y, in.z - mn.z, in.w - mn.w};
        float ms[4] = {mn.x, mn.y, mn.z, mn.w};
        float dq[4], sy[4];
        #pragma unroll
        for (int k = 0; k < 4; ++k) {
            float v = vs[k];
            int lo = 0, hi = LVL;
            #pragma unroll
            for (int s = 0; s < 8; ++s) {
                int mid = (lo + hi) >> 1;
                bool r = (s_uv[mid] < v);
                lo = r ? (mid + 1) : lo;
                hi = r ? hi : mid;
            }
            int idx = min(max(lo, 1), LVL - 1);
            float left = s_uv[idx - 1], right = s_uv[idx];
            bool tl = (fabsf(v - left) <= fabsf(v - right));
            sy[k] = (float)(tl ? idx - 1 : idx);
            dq[k] = (tl ? left : right) + ms[k];
        }
        reinterpret_cast<float4*>(out_deq)[i] = make_float4(dq[0], dq[1], dq[2], dq[3]);
        reinterpret_cast<float4*>(out_sym)[i] = make_float4(sy[0], sy[1], sy[2], sy[3]);
    }
    if (blockIdx.x == 0 && threadIdx.x == 0) {
        for (int j = n4 * 4; j < n; ++j) {
            float m = means[j];
            float v = inputs[j] - m;
            int lo = 0, hi = LVL;
            for (int s = 0; s < 8; ++s) {
                int mid = (lo + hi) >> 1;
                bool r = (s_uv[mid] < v);
                lo = r ? (mid + 1) : lo;
                hi = r ? hi : mid;
            }
            int idx = min(max(lo, 1), LVL - 1);
            float left = s_uv[idx - 1], right = s_uv[idx];
            bool tl = fabsf(v - left) <= fabsf(v - right);
            out_deq[j] = (tl ? left : right) + m;
            out_sym[j] = (float)(tl ? idx - 1 : idx);
        }
    }
}

extern "C" void kernel_launch(void* const* d_in, const int* in_sizes, int n_in,
                              void* d_out, int out_size, void* d_ws, size_t ws_size,
                              hipStream_t stream)
{
    const float* inputs = (const float*)d_in[0];
    const float* means  = (const float*)d_in[1];
    const float* uv     = (const float*)d_in[2];

    int n  = in_sizes[0];        // 12,582,912
    int n4 = n / 4;

    float* out     = (float*)d_out;
    float* out_deq = out;        // first N: dequant
    float* out_sym = out + n;    // second N: symbols (exact float values)

    size_t need = (size_t)NB * sizeof(float4) + LVL * sizeof(float);  // 17.4 KB
    if (d_ws != nullptr && ws_size >= need) {
        float4* lut = (float4*)d_ws;
        float*  thr = (float*)((char*)d_ws + (size_t)NB * sizeof(float4));
        agc_build_lut<<<NB / 256, 256, 0, stream>>>(uv, lut, thr);

        int per_blk = 256 * QPT;                       // quads per block
        int nfull   = n4 / per_blk;                    // fully-covered blocks
        int blocks  = (n4 + per_blk - 1) / per_blk;    // 3072 for this shape
        if (blocks < 1) blocks = 1;
        agc_quant_lut<<<blocks, 256, 0, stream>>>(
            inputs, means, uv, (const f32x4*)lut, thr,
            out_deq, out_sym, n4, n, nfull);
    } else {
        int blocks = (n4 + 255) / 256;
        if (blocks < 1) blocks = 1;
        agc_quant_fallback<<<blocks, 256, 0, stream>>>(
            inputs, means, uv, out_deq, out_sym, n4, n);
    }
}